// Round 6
// baseline (221.658 us; speedup 1.0000x reference)
//
#include <hip/hip_runtime.h>

#define Bn 256
#define Tn 512
#define Cn 256
#define Kn 8

typedef __attribute__((ext_vector_type(4))) float f32x4;

// One block per timestep t. 512 threads = 8 waves -> 4 waves/SIMD, 2 blocks/CU
// (LDS ~67 KB). Wave w owns output rows [w*32, w*32+32).
//
// LDS tile: fp8 e4m3, L2-normalized (fp32 norm), paired-K swizzled layout:
// logical k-byte L of row r lives at unit u = ((q*4+kp) ^ (r&7)) (16B), where
// q=(L>>3)&3, kk=L>>5, kp=kk>>1, half=(kk&1)*8, within=L&7. One ds_read_b128
// at (q,kp) feeds the two MFMAs kk=2kp and kk=2kp+1 (k-bytes kk*32+q*8..+8).
__global__ __launch_bounds__(512, 4)
void tcon_k(const float* __restrict__ emb,
            const int* __restrict__ phon,
            const float* __restrict__ wts,
            float* __restrict__ out) {
    __shared__ __align__(16) unsigned char Esh[Bn * Bn];   // 64 KiB fp8
    __shared__ int   pcls[Bn];
    __shared__ float num_s[Bn], den_s[Bn];
    __shared__ float csum[Kn];
    __shared__ int   ccnt[Kn];

    const int t    = blockIdx.x;
    const int tid  = threadIdx.x;
    const int lane = tid & 63;
    const int wave = tid >> 6;

    if (tid < Kn) { csum[tid] = 0.0f; ccnt[tid] = 0; }
    if (tid < Bn) pcls[tid] = phon[tid * Tn + t];

    // ---- Phase 1: load 1KB rows, fp32 norm, fp8 convert, swizzled LDS write.
    // Lane covers k-bytes [4*lane, 4*lane+4): q=(lane>>1)&3, kk=lane>>3.
    {
        const int q8   = (lane >> 1) & 3;
        const int kk8  = lane >> 3;
        const int ubase = (q8 << 2) + (kk8 >> 1);          // pre-XOR unit
        const int obase = ((kk8 & 1) << 3) + ((lane & 1) << 2);
        #pragma unroll 4
        for (int rr = 0; rr < 32; ++rr) {
            const int row = wave * 32 + rr;
            const float4 v = ((const float4*)(emb + ((size_t)row * Tn + t) * Cn))[lane];
            float ss = v.x * v.x + v.y * v.y + v.z * v.z + v.w * v.w;
            #pragma unroll
            for (int m = 1; m <= 32; m <<= 1) ss += __shfl_xor(ss, m, 64);
            const float inv = rsqrtf(fmaxf(ss, 1e-24f));
            int pk = __builtin_amdgcn_cvt_pk_fp8_f32(v.x * inv, v.y * inv, 0, false);
            pk     = __builtin_amdgcn_cvt_pk_fp8_f32(v.z * inv, v.w * inv, pk, true);
            *(int*)&Esh[row * 256 + ((ubase ^ (row & 7)) << 4) + obase] = pk;
        }
    }
    __syncthreads();

    // ---- Phase 2: Gram strips via fp8 MFMA + fused epilogue ----
    const int q   = lane >> 4;
    const int l15 = lane & 15;
    const int e3  = l15 & 7;        // == row&7 for every fragment row we read
    const int i0  = wave * 32;

    float num_p[8], den_p[8];
    int   pi[8];
    #pragma unroll
    for (int e = 0; e < 8; ++e) {
        const int irow = i0 + (e >> 2) * 16 + q * 4 + (e & 3);
        num_p[e] = 0.0f; den_p[e] = 0.0f;
        pi[e]    = pcls[irow];
    }

    // Hoist A fragments: rows i0+{0,16}+l15, all 4 kp units. 32 VGPRs.
    ulonglong2 afr[2][4];
    #pragma unroll
    for (int m = 0; m < 2; ++m)
        #pragma unroll
        for (int kp = 0; kp < 4; ++kp)
            afr[m][kp] = *(const ulonglong2*)
                &Esh[(i0 + m * 16 + l15) * 256 + ((((q << 2) + kp) ^ e3) << 4)];

    f32x4 acc[2][4];
    for (int s = 0; s < 4; ++s) {
        const int jb = s * 64;
        #pragma unroll
        for (int m = 0; m < 2; ++m)
            #pragma unroll
            for (int n = 0; n < 4; ++n)
                acc[m][n] = (f32x4){0.f, 0.f, 0.f, 0.f};

        #pragma unroll
        for (int kp = 0; kp < 4; ++kp) {
            const int sw = (((q << 2) + kp) ^ e3) << 4;
            ulonglong2 bb[4];
            #pragma unroll
            for (int n = 0; n < 4; ++n)
                bb[n] = *(const ulonglong2*)&Esh[(jb + n * 16 + l15) * 256 + sw];
            #pragma unroll
            for (int m = 0; m < 2; ++m)
                #pragma unroll
                for (int n = 0; n < 4; ++n) {
                    acc[m][n] = __builtin_amdgcn_mfma_f32_16x16x32_fp8_fp8(
                        (long)afr[m][kp].x, (long)bb[n].x, acc[m][n], 0, 0, 0);
                    acc[m][n] = __builtin_amdgcn_mfma_f32_16x16x32_fp8_fp8(
                        (long)afr[m][kp].y, (long)bb[n].y, acc[m][n], 0, 0, 0);
                }
        }

        #pragma unroll
        for (int n = 0; n < 4; ++n) {
            const int j  = jb + n * 16 + l15;
            const int pj = pcls[j];
            #pragma unroll
            for (int m = 0; m < 2; ++m)
                #pragma unroll
                for (int r = 0; r < 4; ++r) {
                    const int e  = m * 4 + r;
                    const int ir = i0 + m * 16 + q * 4 + r;
                    const float ex = __expf(acc[m][n][r]);
                    const bool nd = (ir != j);
                    den_p[e] += nd ? ex : 0.0f;
                    num_p[e] += (nd && (pj == pi[e])) ? ex : 0.0f;
                }
        }
    }

    // Reduce across the 16 l15 lanes of each quad; each row owned by 1 wave.
    #pragma unroll
    for (int e = 0; e < 8; ++e) {
        float n = num_p[e], d = den_p[e];
        #pragma unroll
        for (int m = 1; m <= 8; m <<= 1) {
            n += __shfl_xor(n, m, 64);
            d += __shfl_xor(d, m, 64);
        }
        if (l15 == e) {
            const int irow = i0 + (e >> 2) * 16 + q * 4 + (e & 3);
            num_s[irow] = n;
            den_s[irow] = d;
        }
    }
    __syncthreads();

    // ---- Phase 3: per-sample loss, class means, weighted mean ----
    if (tid < Bn) {
        const float ps = __logf(den_s[tid] + 1e-6f) - __logf(num_s[tid]);
        atomicAdd(&csum[pcls[tid]], ps);
        atomicAdd(&ccnt[pcls[tid]], 1);
    }
    __syncthreads();

    if (tid == 0) {
        float accv = 0.0f; int np = 0;
        #pragma unroll
        for (int k = 0; k < Kn; ++k)
            if (ccnt[k] > 0) { accv += (csum[k] / (float)ccnt[k]) * wts[k]; ++np; }
        atomicAdd(out, (accv / (float)np) * (1.0f / (float)Tn));
    }
}

extern "C" void kernel_launch(void* const* d_in, const int* in_sizes, int n_in,
                              void* d_out, int out_size, void* d_ws, size_t ws_size,
                              hipStream_t stream) {
    const float* emb  = (const float*)d_in[0];
    const int*   phon = (const int*)d_in[1];
    const float* wts  = (const float*)d_in[2];
    float*       out  = (float*)d_out;

    hipMemsetAsync(out, 0, sizeof(float), stream);
    tcon_k<<<Tn, 512, 0, stream>>>(emb, phon, wts, out);
}

// Round 7
// 216.422 us; speedup vs baseline: 1.0242x; 1.0242x over previous
//
#include <hip/hip_runtime.h>

#define Bn 256
#define Tn 512
#define Cn 256
#define Kn 8

typedef __attribute__((ext_vector_type(4))) float f32x4;

// One block per timestep t. 512 threads = 8 waves, 4/SIMD, 2 blocks/CU
// (LDS ~67 KB, regs <=128/wave -- NO hoisting, NO acc across barriers).
//
// LDS tile: fp8 e4m3, L2-normalized (fp32 norm), paired-K swizzle:
// logical 8B half-unit b=kk*4+q of row r -> physical 16B unit
// u=((q*4+kp)^(r&7)), 8B half kk&1 (kp=kk>>1). One ds_read_b128 at (q,kp)
// feeds the MFMAs for kk=2kp and kk=2kp+1.
__global__ __launch_bounds__(512, 4)
void tcon_k(const float* __restrict__ emb,
            const int* __restrict__ phon,
            const float* __restrict__ wts,
            float* __restrict__ out) {
    __shared__ __align__(16) unsigned char Esh[Bn * Bn];   // 64 KiB fp8
    __shared__ int   pcls[Bn];
    __shared__ float num_s[Bn], den_s[Bn];
    __shared__ float csum[Kn];
    __shared__ int   ccnt[Kn];

    const int t    = blockIdx.x;
    const int tid  = threadIdx.x;
    const int lane = tid & 63;
    const int wave = tid >> 6;

    if (tid < Kn) { csum[tid] = 0.0f; ccnt[tid] = 0; }
    if (tid < Bn) pcls[tid] = phon[tid * Tn + t];

    // ---- Phase 1: 32 lanes <-> one row (8 floats/lane). Half-wave 5-step
    // shuffle reduce for the fp32 norm, normalize, fp8-convert, swizzled write.
    {
        const int b     = lane & 31;            // 8-float chunk id within row
        const int q     = b & 3;
        const int kk    = b >> 2;
        const int ubase = (q << 2) + (kk >> 1);
        const int half8 = (kk & 1) << 3;
        #pragma unroll 4
        for (int it = 0; it < 16; ++it) {
            const int row = wave * 2 + (lane >> 5) + it * 16;
            const float4* p = (const float4*)(emb + ((size_t)row * Tn + t) * Cn) + 2 * b;
            const float4 v0 = p[0];
            const float4 v1 = p[1];
            float ss = v0.x*v0.x + v0.y*v0.y + v0.z*v0.z + v0.w*v0.w
                     + v1.x*v1.x + v1.y*v1.y + v1.z*v1.z + v1.w*v1.w;
            #pragma unroll
            for (int m = 1; m <= 16; m <<= 1) ss += __shfl_xor(ss, m, 64);
            const float inv = rsqrtf(fmaxf(ss, 1e-24f));
            int lo = __builtin_amdgcn_cvt_pk_fp8_f32(v0.x * inv, v0.y * inv, 0, false);
            lo     = __builtin_amdgcn_cvt_pk_fp8_f32(v0.z * inv, v0.w * inv, lo, true);
            int hi = __builtin_amdgcn_cvt_pk_fp8_f32(v1.x * inv, v1.y * inv, 0, false);
            hi     = __builtin_amdgcn_cvt_pk_fp8_f32(v1.z * inv, v1.w * inv, hi, true);
            int2 pk; pk.x = lo; pk.y = hi;
            *(int2*)&Esh[row * 256 + ((ubase ^ (row & 7)) << 4) + half8] = pk;
        }
    }
    __syncthreads();

    // ---- Phase 2: Gram strips via fp8 MFMA + fused epilogue (R5 body) ----
    const int q   = lane >> 4;
    const int l15 = lane & 15;
    const int e3  = l15 & 7;        // == row&7 for every fragment row we read
    const int i0  = wave * 32;

    float num_p[8], den_p[8];
    int   pi[8];
    #pragma unroll
    for (int e = 0; e < 8; ++e) {
        const int irow = i0 + (e >> 2) * 16 + q * 4 + (e & 3);
        num_p[e] = 0.0f; den_p[e] = 0.0f;
        pi[e]    = pcls[irow];
    }

    f32x4 acc[2][4];
    for (int s = 0; s < 4; ++s) {
        const int jb = s * 64;
        #pragma unroll
        for (int m = 0; m < 2; ++m)
            #pragma unroll
            for (int n = 0; n < 4; ++n)
                acc[m][n] = (f32x4){0.f, 0.f, 0.f, 0.f};

        #pragma unroll
        for (int kp = 0; kp < 4; ++kp) {
            const int sw = (((q << 2) + kp) ^ e3) << 4;
            ulonglong2 a[2], bb[4];
            #pragma unroll
            for (int m = 0; m < 2; ++m)
                a[m] = *(const ulonglong2*)&Esh[(i0 + m * 16 + l15) * 256 + sw];
            #pragma unroll
            for (int n = 0; n < 4; ++n)
                bb[n] = *(const ulonglong2*)&Esh[(jb + n * 16 + l15) * 256 + sw];
            #pragma unroll
            for (int m = 0; m < 2; ++m)
                #pragma unroll
                for (int n = 0; n < 4; ++n) {
                    acc[m][n] = __builtin_amdgcn_mfma_f32_16x16x32_fp8_fp8(
                        (long)a[m].x, (long)bb[n].x, acc[m][n], 0, 0, 0);
                    acc[m][n] = __builtin_amdgcn_mfma_f32_16x16x32_fp8_fp8(
                        (long)a[m].y, (long)bb[n].y, acc[m][n], 0, 0, 0);
                }
        }

        #pragma unroll
        for (int n = 0; n < 4; ++n) {
            const int j  = jb + n * 16 + l15;
            const int pj = pcls[j];
            #pragma unroll
            for (int m = 0; m < 2; ++m)
                #pragma unroll
                for (int r = 0; r < 4; ++r) {
                    const int e  = m * 4 + r;
                    const int ir = i0 + m * 16 + q * 4 + r;
                    const float ex = __expf(acc[m][n][r]);
                    const bool nd = (ir != j);
                    den_p[e] += nd ? ex : 0.0f;
                    num_p[e] += (nd && (pj == pi[e])) ? ex : 0.0f;
                }
        }
    }

    // Reduce across the 16 l15 lanes of each quad; each row owned by 1 wave.
    #pragma unroll
    for (int e = 0; e < 8; ++e) {
        float n = num_p[e], d = den_p[e];
        #pragma unroll
        for (int m = 1; m <= 8; m <<= 1) {
            n += __shfl_xor(n, m, 64);
            d += __shfl_xor(d, m, 64);
        }
        if (l15 == e) {
            const int irow = i0 + (e >> 2) * 16 + q * 4 + (e & 3);
            num_s[irow] = n;
            den_s[irow] = d;
        }
    }
    __syncthreads();

    // ---- Phase 3: per-sample loss, class means, weighted mean ----
    if (tid < Bn) {
        const float ps = __logf(den_s[tid] + 1e-6f) - __logf(num_s[tid]);
        atomicAdd(&csum[pcls[tid]], ps);
        atomicAdd(&ccnt[pcls[tid]], 1);
    }
    __syncthreads();

    if (tid == 0) {
        float accv = 0.0f; int np = 0;
        #pragma unroll
        for (int k = 0; k < Kn; ++k)
            if (ccnt[k] > 0) { accv += (csum[k] / (float)ccnt[k]) * wts[k]; ++np; }
        atomicAdd(out, (accv / (float)np) * (1.0f / (float)Tn));
    }
}

extern "C" void kernel_launch(void* const* d_in, const int* in_sizes, int n_in,
                              void* d_out, int out_size, void* d_ws, size_t ws_size,
                              hipStream_t stream) {
    const float* emb  = (const float*)d_in[0];
    const int*   phon = (const int*)d_in[1];
    const float* wts  = (const float*)d_in[2];
    float*       out  = (float*)d_out;

    hipMemsetAsync(out, 0, sizeof(float), stream);
    tcon_k<<<Tn, 512, 0, stream>>>(emb, phon, wts, out);
}